// Round 3
// baseline (212.529 us; speedup 1.0000x reference)
//
#include <hip/hip_runtime.h>
#include <hip/hip_bf16.h>
#include <stdint.h>

#define N_NODES  20000
#define N_EDGES  160000
#define F_IN     512
#define HIDDEN   512
#define N_CLS    40
#define M_PAD    20096   // 157 * 128
#define DEG_PAD  20480   // 1024 * 20

typedef __bf16 bf16;
typedef __attribute__((ext_vector_type(8))) __bf16 bf16x8;
typedef __attribute__((ext_vector_type(4))) float floatx4;

__device__ inline floatx4 zero4() { floatx4 z = {0.f, 0.f, 0.f, 0.f}; return z; }

// async global->LDS, 16B per lane; LDS dest = wave-uniform base + lane*16
typedef __attribute__((address_space(3))) uint32_t lds_u32;
typedef __attribute__((address_space(1))) const uint32_t glb_u32;
__device__ inline void ldst16(const bf16* g, bf16* l) {
    __builtin_amdgcn_global_load_lds((glb_u32*)g, (lds_u32*)l, 16, 0, 0);
}

// ---------------- prep: convert_x | W1^T | degree ----------------
#define NB_CONV 5024
#define NB_W1T  128
#define NB_DEG  625
#define NB_PREP (NB_CONV + NB_W1T + NB_DEG)

__global__ void prep_kernel(const float* __restrict__ x, bf16* __restrict__ xb,
                            const float* __restrict__ W1, bf16* __restrict__ W1T,
                            const int* __restrict__ ei, int* __restrict__ deg) {
    const int b = blockIdx.x, tid = threadIdx.x;
    if (b < NB_CONV) {
        long e0 = ((long)b * 256 + tid) * 8;
        int row = (int)(e0 >> 9);
        bf16x8 v;
        if (row < N_NODES) {
            const float4* p = (const float4*)(x + e0);
            float4 f0 = p[0], f1 = p[1];
            v[0] = (bf16)f0.x; v[1] = (bf16)f0.y; v[2] = (bf16)f0.z; v[3] = (bf16)f0.w;
            v[4] = (bf16)f1.x; v[5] = (bf16)f1.y; v[6] = (bf16)f1.z; v[7] = (bf16)f1.w;
        } else {
            for (int j = 0; j < 8; ++j) v[j] = (bf16)0.f;
        }
        *(bf16x8*)(xb + e0) = v;
    } else if (b < NB_CONV + NB_W1T) {
        int t  = (b - NB_CONV) * 256 + tid;    // < 32768
        int n  = t & 511;
        int k0 = (t >> 9) * 8;
        bf16x8 v;
        for (int j = 0; j < 8; ++j) v[j] = (bf16)W1[((k0 + j) << 9) + n];
        *(bf16x8*)(W1T + n * 512 + k0) = v;
    } else {
        int e = (b - NB_CONV - NB_W1T) * 256 + tid;
        if (e < N_EDGES) atomicAdd(&deg[ei[N_EDGES + e]], 1);
    }
}

// ---------------- scan (block 0) + w2pack (blocks 1..24), 1024 threads ----------------
// shfl-based scan: per-thread 20 elems, wave scan via shfl_up, 2 barriers total.

__global__ __launch_bounds__(1024) void scan_w2p_kernel(const int* __restrict__ deg,
                                                        int* __restrict__ rowptr,
                                                        int* __restrict__ cur,
                                                        float* __restrict__ dis,
                                                        const float* __restrict__ W2,
                                                        bf16* __restrict__ W2P) {
    const int tid = threadIdx.x;
    if (blockIdx.x != 0) {
        // W2 (512x40) -> gemm2 B-fragment order, N padded to 48
        int t = (blockIdx.x - 1) * 1024 + tid;   // < 24576
        int j = t & 7; int e = t >> 3;
        int lane = e & 63; e >>= 6;
        int nb = e % 3; int kt = e / 3;
        int k = kt * 32 + (lane >> 4) * 8 + j;
        int n = nb * 16 + (lane & 15);
        float v = (n < N_CLS) ? W2[k * N_CLS + n] : 0.f;
        W2P[t] = (bf16)v;
        return;
    }
    __shared__ int shW[16];
    const int lane = tid & 63, w = tid >> 6;
    const int base = tid * 20;
    int vals[20];
    {
        const int4* dp = (const int4*)(deg + base);
        for (int q = 0; q < 5; ++q) {
            int4 v = dp[q];
            vals[q * 4 + 0] = v.x; vals[q * 4 + 1] = v.y;
            vals[q * 4 + 2] = v.z; vals[q * 4 + 3] = v.w;
        }
    }
    int loc[20];
    int sum = 0;
    for (int j = 0; j < 20; ++j) { loc[j] = sum; sum += vals[j]; }
    // inclusive scan of per-thread sums within the wave
    int inc = sum;
    for (int off = 1; off < 64; off <<= 1) {
        int u = __shfl_up(inc, off, 64);
        if (lane >= off) inc += u;
    }
    if (lane == 63) shW[w] = inc;        // wave totals
    __syncthreads();
    if (w == 0 && lane < 16) {
        int s = shW[lane];
        int si = s;
        for (int off = 1; off < 16; off <<= 1) {
            int u = __shfl_up(si, off, 64);
            if (lane >= off) si += u;
        }
        shW[lane] = si - s;              // exclusive wave offsets
    }
    __syncthreads();
    const int excl = shW[w] + (inc - sum);   // exclusive prefix for this thread
    for (int j = 0; j < 20; ++j) {
        int idx = base + j;
        if (idx < N_NODES) {
            int r = excl + loc[j];
            rowptr[idx] = r;
            cur[idx]    = r;
            dis[idx]    = rsqrtf((float)(vals[j] + 1));
        }
    }
    if (tid == 1023) rowptr[N_NODES] = excl + sum;
}

// ---------------- GEMM1 (blocks 0..627) + CSR fill (blocks 628..1252) ----------------
// gemm: 128x128 tile, BK=32, global_load_lds width=16 (m97 structure)
// fill: independent of gemm -> rides in the same dispatch

#define NB_GEMM1 628    // 157 * 4
#define NB_FILL  625

__global__ __launch_bounds__(256) void gemm1_fill_kernel(const bf16* __restrict__ A,
                                                         const bf16* __restrict__ BT,
                                                         bf16* __restrict__ C,
                                                         const int* __restrict__ ei,
                                                         int* __restrict__ cur,
                                                         int* __restrict__ col) {
    if (blockIdx.x >= NB_GEMM1) {
        int e = (blockIdx.x - NB_GEMM1) * 256 + threadIdx.x;
        if (e < N_EDGES) {
            int d = ei[N_EDGES + e];
            int pos = atomicAdd(&cur[d], 1);
            col[pos] = ei[e];
        }
        return;
    }
    __shared__ bf16 As[128 * 32];
    __shared__ bf16 Bs[128 * 32];
    const int tid  = threadIdx.x;
    const int lane = tid & 63;
    const int w    = tid >> 6;
    const int wm   = w >> 1, wn = w & 1;
    const int m0   = (blockIdx.x >> 2) * 128;
    const int n0   = (blockIdx.x & 3) * 128;
    const int fr   = lane & 15, fq = lane >> 4;

    floatx4 acc[4][4];
    for (int mb = 0; mb < 4; ++mb)
        for (int nb = 0; nb < 4; ++nb) acc[mb][nb] = zero4();

    const int sr = lane >> 2;
    const int sk = (lane & 3) * 8;
    const bf16* Ag = A  + (long)(m0 + w * 32 + sr) * 512 + sk;
    const bf16* Bg = BT + (long)(n0 + w * 32 + sr) * 512 + sk;
    bf16* Asw = As + w * 1024;
    bf16* Bsw = Bs + w * 1024;

    for (int kt = 0; kt < 16; ++kt) {
        const int k0 = kt * 32;
        __syncthreads();
        ldst16(Ag + k0,            Asw);
        ldst16(Ag + k0 + 16 * 512, Asw + 512);
        ldst16(Bg + k0,            Bsw);
        ldst16(Bg + k0 + 16 * 512, Bsw + 512);
        __syncthreads();
        bf16x8 af[4], bfv[4];
        for (int mb = 0; mb < 4; ++mb)
            af[mb]  = *(const bf16x8*)(As + (wm * 64 + mb * 16 + fr) * 32 + fq * 8);
        for (int nb = 0; nb < 4; ++nb)
            bfv[nb] = *(const bf16x8*)(Bs + (wn * 64 + nb * 16 + fr) * 32 + fq * 8);
        for (int mb = 0; mb < 4; ++mb)
            for (int nb = 0; nb < 4; ++nb)
                acc[mb][nb] = __builtin_amdgcn_mfma_f32_16x16x32_bf16(af[mb], bfv[nb], acc[mb][nb], 0, 0, 0);
    }

    for (int mb = 0; mb < 4; ++mb)
        for (int nb = 0; nb < 4; ++nb) {
            int row0 = m0 + wm * 64 + mb * 16 + fq * 4;
            int c    = n0 + wn * 64 + nb * 16 + fr;
            for (int r = 0; r < 4; ++r)
                C[(long)(row0 + r) * 512 + c] = (bf16)acc[mb][nb][r];
        }
}

// ---------------- aggregation 1: a1 = relu(Anorm @ h1 + b1), 4 nodes/block ----------------

__global__ __launch_bounds__(256) void agg1_kernel(const bf16* __restrict__ H1,
                                                   const float* __restrict__ dis,
                                                   const int* __restrict__ rowptr,
                                                   const int* __restrict__ col,
                                                   const float* __restrict__ b1,
                                                   bf16* __restrict__ A1) {
    const int i = blockIdx.x * 4 + (threadIdx.x >> 6);
    const int l = threadIdx.x & 63;
    bf16* outp = A1 + (long)i * 512 + l * 8;
    if (i >= N_NODES) {
        bf16x8 z;
        for (int j = 0; j < 8; ++j) z[j] = (bf16)0.f;
        *(bf16x8*)outp = z;
        return;
    }
    const float di = dis[i];
    float acc[8];
    {
        bf16x8 v = *(const bf16x8*)(H1 + (long)i * 512 + l * 8);
        const float wi = di * di;
        for (int j = 0; j < 8; ++j) acc[j] = (float)v[j] * wi;
    }
    const int e1 = rowptr[i + 1];
    for (int e = rowptr[i]; e < e1; ++e) {
        const int s = col[e];
        const float wt = dis[s] * di;
        bf16x8 u = *(const bf16x8*)(H1 + (long)s * 512 + l * 8);
        for (int j = 0; j < 8; ++j) acc[j] += (float)u[j] * wt;
    }
    const float4* bp = (const float4*)(b1 + l * 8);
    float4 c0 = bp[0], c1 = bp[1];
    float bb[8] = {c0.x, c0.y, c0.z, c0.w, c1.x, c1.y, c1.z, c1.w};
    bf16x8 o;
    for (int j = 0; j < 8; ++j) {
        float f = acc[j] + bb[j];
        f = f > 0.f ? f : 0.f;
        o[j] = (bf16)f;
    }
    *(bf16x8*)outp = o;
}

// ---------------- GEMM2: H2[M_PAD,48] = A1 @ W2P ----------------

__global__ __launch_bounds__(256) void gemm2_kernel(const bf16* __restrict__ A,
                                                    const bf16* __restrict__ P,
                                                    float* __restrict__ H2) {
    const int tid = threadIdx.x, lane = tid & 63, w = tid >> 6;
    const int m0 = blockIdx.x * 64 + w * 16;
    const int fr = lane & 15, fq = lane >> 4;
    const bf16* Ap = A + (long)(m0 + fr) * 512 + fq * 8;
    floatx4 acc[3];
    for (int nb = 0; nb < 3; ++nb) acc[nb] = zero4();
    for (int kt = 0; kt < 16; ++kt) {
        bf16x8 af = *(const bf16x8*)(Ap + kt * 32);
        for (int nb = 0; nb < 3; ++nb) {
            bf16x8 bfr = *(const bf16x8*)(P + ((kt * 3 + nb) * 64 + lane) * 8);
            acc[nb] = __builtin_amdgcn_mfma_f32_16x16x32_bf16(af, bfr, acc[nb], 0, 0, 0);
        }
    }
    for (int nb = 0; nb < 3; ++nb)
        for (int r = 0; r < 4; ++r)
            H2[(long)(m0 + fq * 4 + r) * 48 + nb * 16 + fr] = acc[nb][r];
}

// ---------------- aggregation 2: out = Anorm @ h2 + b2, 4 nodes/block ----------------

__global__ __launch_bounds__(256) void agg2_kernel(const float* __restrict__ H2,
                                                   const float* __restrict__ dis,
                                                   const int* __restrict__ rowptr,
                                                   const int* __restrict__ col,
                                                   const float* __restrict__ b2,
                                                   float* __restrict__ out) {
    const int i = blockIdx.x * 4 + (threadIdx.x >> 6);
    const int l = threadIdx.x & 63;
    if (l >= N_CLS || i >= N_NODES) return;
    const float di = dis[i];
    float acc = H2[(long)i * 48 + l] * di * di;
    const int e1 = rowptr[i + 1];
    for (int e = rowptr[i]; e < e1; ++e) {
        const int s = col[e];
        acc += H2[(long)s * 48 + l] * (dis[s] * di);
    }
    out[(long)i * N_CLS + l] = acc + b2[l];
}

// ---------------- launch ----------------

extern "C" void kernel_launch(void* const* d_in, const int* in_sizes, int n_in,
                              void* d_out, int out_size, void* d_ws, size_t ws_size,
                              hipStream_t stream) {
    const float* x  = (const float*)d_in[0];
    const int*   ei = (const int*)d_in[1];
    const float* W1 = (const float*)d_in[2];
    const float* b1 = (const float*)d_in[3];
    const float* W2 = (const float*)d_in[4];
    const float* b2 = (const float*)d_in[5];
    float* out = (float*)d_out;

    char* base = (char*)d_ws;
    size_t o = 0;
    auto alloc = [&](size_t bytes) { size_t r = o; o = (o + bytes + 255) & ~(size_t)255; return r; };
    bf16*  xb   = (bf16*)(base + alloc((size_t)M_PAD * 512 * 2));
    bf16*  w1t  = (bf16*)(base + alloc((size_t)512 * 512 * 2));
    bf16*  w2p  = (bf16*)(base + alloc((size_t)24576 * 2));
    bf16*  h1   = (bf16*)(base + alloc((size_t)M_PAD * 512 * 2));
    bf16*  a1   = (bf16*)(base + alloc((size_t)M_PAD * 512 * 2));
    float* h2   = (float*)(base + alloc((size_t)M_PAD * 48 * 4));
    size_t deg_off = alloc((size_t)DEG_PAD * 4);
    int*   deg  = (int*)(base + deg_off);
    int*   cur  = (int*)(base + alloc((size_t)N_NODES * 4));
    int*   rowp = (int*)(base + alloc((size_t)(N_NODES + 1) * 4));
    int*   col  = (int*)(base + alloc((size_t)N_EDGES * 4));
    float* dis  = (float*)(base + alloc((size_t)N_NODES * 4));

    hipMemsetAsync(deg, 0, (size_t)DEG_PAD * 4, stream);

    prep_kernel<<<NB_PREP, 256, 0, stream>>>(x, xb, W1, w1t, ei, deg);
    scan_w2p_kernel<<<25, 1024, 0, stream>>>(deg, rowp, cur, dis, W2, w2p);
    gemm1_fill_kernel<<<NB_GEMM1 + NB_FILL, 256, 0, stream>>>(xb, w1t, h1, ei, cur, col);
    agg1_kernel<<<M_PAD / 4, 256, 0, stream>>>(h1, dis, rowp, col, b1, a1);
    gemm2_kernel<<<M_PAD / 64, 256, 0, stream>>>(a1, w2p, h2);
    agg2_kernel<<<N_NODES / 4, 256, 0, stream>>>(h2, dis, rowp, col, b2, out);
}